// Round 1
// baseline (3617.307 us; speedup 1.0000x reference)
//
#include <hip/hip_runtime.h>
#include <hip/hip_bf16.h>
#include <math.h>

#define T     2048
#define HID   1536
#define NH    12
#define DK    128
#define DV    128
#define CONVK 4

__device__ __forceinline__ float siluf(float x) {
    return x / (1.0f + __expf(-x));
}

// ---------------------------------------------------------------------------
// Tiled SGEMM: C = op(A @ B). A (M,K) row-major, B (K,N) row-major.
// BM=BN=128, BK=8, 256 threads, 8x8 micro-tile per thread.
// M always multiple of 128 here; K multiple of 8; N guarded (N=192 case).
// OP: 0 = identity, 1 = silu
// ---------------------------------------------------------------------------
template<int OP>
__global__ __launch_bounds__(256) void sgemm(const float* __restrict__ A,
                                             const float* __restrict__ B,
                                             float* __restrict__ C,
                                             int M, int N, int K) {
    const int BM = 128, BN = 128, BK = 8;
    __shared__ float As[BK][BM + 4];
    __shared__ float Bs[BK][BN + 4];

    const int tid = threadIdx.x;
    const int tx = tid & 15;        // 0..15 -> N direction (8 cols each)
    const int ty = tid >> 4;        // 0..15 -> M direction (8 rows each)
    const int rowBase = blockIdx.y * BM;
    const int colBase = blockIdx.x * BN;

    const int arow = tid >> 1;            // 0..127
    const int acol = (tid & 1) * 4;       // 0 or 4
    const int brow = tid >> 5;            // 0..7
    const int bcol = (tid & 31) * 4;      // 0..124

    float acc[8][8];
#pragma unroll
    for (int i = 0; i < 8; i++)
#pragma unroll
        for (int j = 0; j < 8; j++) acc[i][j] = 0.0f;

    for (int k0 = 0; k0 < K; k0 += BK) {
        // A tile: 128 rows x 8 k
        float4 av = *(const float4*)(A + (size_t)(rowBase + arow) * K + k0 + acol);
        As[acol + 0][arow] = av.x;
        As[acol + 1][arow] = av.y;
        As[acol + 2][arow] = av.z;
        As[acol + 3][arow] = av.w;
        // B tile: 8 k x 128 cols (zero-fill out-of-range cols)
        float4 bv;
        if (colBase + bcol < N)
            bv = *(const float4*)(B + (size_t)(k0 + brow) * N + colBase + bcol);
        else
            bv = make_float4(0.f, 0.f, 0.f, 0.f);
        *(float4*)&Bs[brow][bcol] = bv;
        __syncthreads();

#pragma unroll
        for (int kk = 0; kk < BK; kk++) {
            float a0[8], b0[8];
            *(float4*)&a0[0] = *(const float4*)&As[kk][ty * 8];
            *(float4*)&a0[4] = *(const float4*)&As[kk][ty * 8 + 4];
            *(float4*)&b0[0] = *(const float4*)&Bs[kk][tx * 8];
            *(float4*)&b0[4] = *(const float4*)&Bs[kk][tx * 8 + 4];
#pragma unroll
            for (int i = 0; i < 8; i++)
#pragma unroll
                for (int j = 0; j < 8; j++) acc[i][j] += a0[i] * b0[j];
        }
        __syncthreads();
    }

#pragma unroll
    for (int i = 0; i < 8; i++) {
        const int row = rowBase + ty * 8 + i;
        float* Crow = C + (size_t)row * N + colBase + tx * 8;
#pragma unroll
        for (int j4 = 0; j4 < 8; j4 += 4) {
            const int col = colBase + tx * 8 + j4;
            if (col < N) {
                float4 v;
                float x0 = acc[i][j4 + 0], x1 = acc[i][j4 + 1];
                float x2 = acc[i][j4 + 2], x3 = acc[i][j4 + 3];
                if (OP == 1) { x0 = siluf(x0); x1 = siluf(x1); x2 = siluf(x2); x3 = siluf(x3); }
                v.x = x0; v.y = x1; v.z = x2; v.w = x3;
                *(float4*)(Crow + j4) = v;
            }
        }
    }
}

// ---------------------------------------------------------------------------
// beta[t,h] = sigmoid(hs[t,:] @ Wb[:,h]); g[t,h] = -exp(A_log)*softplus(hs@Wa + dt_bias)
// One wave per (t, j) output, j in [0,24): j<12 -> beta, j>=12 -> g.
// ---------------------------------------------------------------------------
__global__ __launch_bounds__(256) void bg_kernel(const float* __restrict__ hs,
                                                 const float* __restrict__ Wb,
                                                 const float* __restrict__ Wa,
                                                 const float* __restrict__ A_log,
                                                 const float* __restrict__ dt_bias,
                                                 float* __restrict__ beta,
                                                 float* __restrict__ g) {
    const int gw = (blockIdx.x * 256 + threadIdx.x) >> 6;
    const int lane = threadIdx.x & 63;
    if (gw >= T * 24) return;
    const int t = gw / 24, j = gw % 24;
    const float* W = (j < 12) ? (Wb + j) : (Wa + (j - 12));
    float s = 0.0f;
    for (int kk = lane; kk < HID; kk += 64)
        s += hs[(size_t)t * HID + kk] * W[(size_t)kk * NH];
    s += __shfl_xor(s, 1);  s += __shfl_xor(s, 2);  s += __shfl_xor(s, 4);
    s += __shfl_xor(s, 8);  s += __shfl_xor(s, 16); s += __shfl_xor(s, 32);
    if (lane == 0) {
        if (j < 12) {
            beta[t * NH + j] = 1.0f / (1.0f + __expf(-s));
        } else {
            const int hh = j - 12;
            const float x = s + dt_bias[hh];
            const float sp = (x > 20.0f) ? x : log1pf(__expf(x));
            g[t * NH + hh] = -__expf(A_log[hh]) * sp;
        }
    }
}

// ---------------------------------------------------------------------------
// Dynamic causal conv: v[t,d] = silu( sum_i vpre[t-3+i, d] * w[t, d*4+i] )
// ---------------------------------------------------------------------------
__global__ __launch_bounds__(256) void conv_kernel(const float* __restrict__ vpre,
                                                   const float* __restrict__ w,
                                                   float* __restrict__ v) {
    const int idx = blockIdx.x * 256 + threadIdx.x;   // t*1536 + d
    if (idx >= T * HID) return;
    const int t = idx / HID, d = idx % HID;
    const float4 wv = *(const float4*)(w + (size_t)t * (HID * CONVK) + d * 4);
    const float w4[4] = { wv.x, wv.y, wv.z, wv.w };
    float acc = 0.0f;
#pragma unroll
    for (int i = 0; i < CONVK; i++) {
        const int ts = t - (CONVK - 1) + i;
        if (ts >= 0) acc += vpre[(size_t)ts * HID + d] * w4[i];
    }
    v[idx] = siluf(acc);
}

// ---------------------------------------------------------------------------
// Sequential gated delta rule.
// Grid: 48 blocks = 12 heads x 4 v-blocks. Block: 256 thr = 4 waves.
// Wave handles 8 v-columns; lane = (kgroup<<3) | col; each thread owns
// S[kgroup*16 .. +15][col] (16 regs). Per-step k-reduction via 3 shfl_xor.
// ---------------------------------------------------------------------------
__global__ __launch_bounds__(256) void delta_kernel(const float* __restrict__ q,
                                                    const float* __restrict__ k,
                                                    const float* __restrict__ v,
                                                    const float* __restrict__ g,
                                                    const float* __restrict__ beta,
                                                    float* __restrict__ o) {
    __shared__ float sDecay[T];
    __shared__ float sBeta[T];
    const int h = blockIdx.x >> 2;
    const int vblk = blockIdx.x & 3;
    for (int i = threadIdx.x; i < T; i += 256) {
        sDecay[i] = __expf(g[i * NH + h]);
        sBeta[i]  = beta[i * NH + h];
    }
    __syncthreads();

    const int wave = threadIdx.x >> 6;
    const int lane = threadIdx.x & 63;
    const int c  = lane & 7;        // column within wave
    const int kg = lane >> 3;       // k-group 0..7 (16 k each)
    const int col = vblk * 32 + wave * 8 + c;    // global dv 0..127

    const float* kbase = k + h * DK + kg * 16;
    const float* qbase = q + h * DK + kg * 16;
    const float* vbase = v + h * DV + col;

    float S[16];
#pragma unroll
    for (int j = 0; j < 16; j++) S[j] = 0.0f;

    float kr[16], qr[16], va;
    {
        const float4* kp = (const float4*)kbase;
        const float4* qp = (const float4*)qbase;
#pragma unroll
        for (int i = 0; i < 4; i++) {
            *(float4*)&kr[4 * i] = kp[i];
            *(float4*)&qr[4 * i] = qp[i];
        }
        va = vbase[0];
    }

    const float scale = 0.08838834764831845f;   // DK^-0.5

    for (int t = 0; t < T; t++) {
        // prefetch t+1 (clamped address keeps it in-bounds; dead on last iter)
        const int tn = (t + 1 < T) ? (t + 1) : t;
        float krn[16], qrn[16], van;
        {
            const float4* kp = (const float4*)(kbase + (size_t)tn * HID);
            const float4* qp = (const float4*)(qbase + (size_t)tn * HID);
#pragma unroll
            for (int i = 0; i < 4; i++) {
                *(float4*)&krn[4 * i] = kp[i];
                *(float4*)&qrn[4 * i] = qp[i];
            }
            van = vbase[(size_t)tn * HID];
        }

        const float dec = sDecay[t];
        const float bt  = sBeta[t];

        float kvp = 0.0f;
#pragma unroll
        for (int j = 0; j < 16; j++) kvp += kr[j] * S[j];
        kvp += __shfl_xor(kvp, 8);
        kvp += __shfl_xor(kvp, 16);
        kvp += __shfl_xor(kvp, 32);

        const float delta = (va - dec * kvp) * bt;

        float op = 0.0f;
#pragma unroll
        for (int j = 0; j < 16; j++) {
            S[j] = S[j] * dec + kr[j] * delta;
            op += qr[j] * S[j];
        }
        op += __shfl_xor(op, 8);
        op += __shfl_xor(op, 16);
        op += __shfl_xor(op, 32);

        if (kg == 0) o[(size_t)t * HID + h * DV + col] = op * scale;

#pragma unroll
        for (int j = 0; j < 16; j++) { kr[j] = krn[j]; qr[j] = qrn[j]; }
        va = van;
    }
}

// ---------------------------------------------------------------------------
// Gated RMSNorm: out = o * rsqrt(mean(o^2, dv)+eps) * nw[dv] * gsil  (per t,h)
// One wave per (t,h); lane covers dv=lane and dv=lane+64.
// ---------------------------------------------------------------------------
__global__ __launch_bounds__(256) void normgate_kernel(const float* __restrict__ o,
                                                       const float* __restrict__ gsil,
                                                       const float* __restrict__ nw,
                                                       float* __restrict__ out) {
    const int gw = (blockIdx.x * 256 + threadIdx.x) >> 6;
    const int lane = threadIdx.x & 63;
    if (gw >= T * NH) return;
    const int t = gw / NH, h = gw % NH;
    const size_t base = (size_t)t * HID + h * DV;
    const float a = o[base + lane];
    const float b = o[base + lane + 64];
    float ss = a * a + b * b;
    ss += __shfl_xor(ss, 1);  ss += __shfl_xor(ss, 2);  ss += __shfl_xor(ss, 4);
    ss += __shfl_xor(ss, 8);  ss += __shfl_xor(ss, 16); ss += __shfl_xor(ss, 32);
    const float r = rsqrtf(ss * (1.0f / 128.0f) + 1e-5f);
    out[base + lane]      = a * r * nw[lane]      * gsil[base + lane];
    out[base + lane + 64] = b * r * nw[lane + 64] * gsil[base + lane + 64];
}

// ---------------------------------------------------------------------------
extern "C" void kernel_launch(void* const* d_in, const int* in_sizes, int n_in,
                              void* d_out, int out_size, void* d_ws, size_t ws_size,
                              hipStream_t stream) {
    const float* hs      = (const float*)d_in[0];
    const float* Wq      = (const float*)d_in[1];
    const float* Wk      = (const float*)d_in[2];
    const float* Wv      = (const float*)d_in[3];
    const float* Wb      = (const float*)d_in[4];
    const float* Wa      = (const float*)d_in[5];
    const float* A_log   = (const float*)d_in[6];
    const float* dt_bias = (const float*)d_in[7];
    const float* Wg1     = (const float*)d_in[8];
    const float* Wg2     = (const float*)d_in[9];
    const float* Wgate   = (const float*)d_in[10];
    const float* norm_w  = (const float*)d_in[11];
    const float* Wo      = (const float*)d_in[12];

    float* ws = (float*)d_ws;
    // workspace layout (floats); overlays are stream-order safe:
    float* q    = ws;                      // 3,145,728
    float* kk   = ws + 3145728;            // 3,145,728
    float* vpre = ws + 6291456;            // 3,145,728
    float* v    = ws + 9437184;            // 3,145,728
    float* w1   = ws + 12582912;           //   393,216
    float* wcv  = ws + 12976128;           // 12,582,912
    float* beta = ws + 25559040;           //    24,576
    float* g    = ws + 25583616;           //    24,576
    float* gsil = vpre;   // reuse: vpre last read by conv_kernel (before gate gemm)
    float* o    = wcv;    // reuse: wcv last read by conv_kernel (before delta)
    float* onorm= q;      // reuse: q last read by delta_kernel (before normgate)

    const dim3 blk(256);
    const dim3 gBig(12, 16);   // N=1536/128, M=2048/128

    sgemm<1><<<gBig, blk, 0, stream>>>(hs, Wq, q,    2048, 1536, 1536);
    sgemm<1><<<gBig, blk, 0, stream>>>(hs, Wk, kk,   2048, 1536, 1536);
    sgemm<0><<<gBig, blk, 0, stream>>>(hs, Wv, vpre, 2048, 1536, 1536);
    sgemm<1><<<dim3(2, 16),  blk, 0, stream>>>(hs, Wg1, w1,  2048, 192, 1536);
    sgemm<0><<<dim3(48, 16), blk, 0, stream>>>(w1, Wg2, wcv, 2048, 6144, 192);
    bg_kernel<<<12288, blk, 0, stream>>>(hs, Wb, Wa, A_log, dt_bias, beta, g);
    conv_kernel<<<(T * HID) / 256, blk, 0, stream>>>(vpre, wcv, v);
    sgemm<1><<<gBig, blk, 0, stream>>>(hs, Wgate, gsil, 2048, 1536, 1536);
    delta_kernel<<<48, blk, 0, stream>>>(q, kk, v, g, beta, o);
    normgate_kernel<<<6144, blk, 0, stream>>>(o, gsil, norm_w, onorm);
    sgemm<0><<<gBig, blk, 0, stream>>>(onorm, Wo, (float*)d_out, 2048, 1536, 1536);
}

// Round 3
// 2497.743 us; speedup vs baseline: 1.4482x; 1.4482x over previous
//
#include <hip/hip_runtime.h>
#include <hip/hip_bf16.h>
#include <math.h>

#define T     2048
#define HID   1536
#define NH    12
#define DK    128
#define DV    128
#define CONVK 4
#define CH    64     // chunk length
#define NC    32     // number of chunks = T/CH

__device__ __forceinline__ float siluf(float x) {
    return x / (1.0f + __expf(-x));
}

// ---------------------------------------------------------------------------
// Tiled SGEMM: C = op(A @ B). (unchanged)
// ---------------------------------------------------------------------------
template<int OP>
__global__ __launch_bounds__(256) void sgemm(const float* __restrict__ A,
                                             const float* __restrict__ B,
                                             float* __restrict__ C,
                                             int M, int N, int K) {
    const int BM = 128, BN = 128, BK = 8;
    __shared__ float As[BK][BM + 4];
    __shared__ float Bs[BK][BN + 4];

    const int tid = threadIdx.x;
    const int tx = tid & 15;
    const int ty = tid >> 4;
    const int rowBase = blockIdx.y * BM;
    const int colBase = blockIdx.x * BN;

    const int arow = tid >> 1;
    const int acol = (tid & 1) * 4;
    const int brow = tid >> 5;
    const int bcol = (tid & 31) * 4;

    float acc[8][8];
#pragma unroll
    for (int i = 0; i < 8; i++)
#pragma unroll
        for (int j = 0; j < 8; j++) acc[i][j] = 0.0f;

    for (int k0 = 0; k0 < K; k0 += BK) {
        float4 av = *(const float4*)(A + (size_t)(rowBase + arow) * K + k0 + acol);
        As[acol + 0][arow] = av.x;
        As[acol + 1][arow] = av.y;
        As[acol + 2][arow] = av.z;
        As[acol + 3][arow] = av.w;
        float4 bv;
        if (colBase + bcol < N)
            bv = *(const float4*)(B + (size_t)(k0 + brow) * N + colBase + bcol);
        else
            bv = make_float4(0.f, 0.f, 0.f, 0.f);
        *(float4*)&Bs[brow][bcol] = bv;
        __syncthreads();

#pragma unroll
        for (int kk = 0; kk < BK; kk++) {
            float a0[8], b0[8];
            *(float4*)&a0[0] = *(const float4*)&As[kk][ty * 8];
            *(float4*)&a0[4] = *(const float4*)&As[kk][ty * 8 + 4];
            *(float4*)&b0[0] = *(const float4*)&Bs[kk][tx * 8];
            *(float4*)&b0[4] = *(const float4*)&Bs[kk][tx * 8 + 4];
#pragma unroll
            for (int i = 0; i < 8; i++)
#pragma unroll
                for (int j = 0; j < 8; j++) acc[i][j] += a0[i] * b0[j];
        }
        __syncthreads();
    }

#pragma unroll
    for (int i = 0; i < 8; i++) {
        const int row = rowBase + ty * 8 + i;
        float* Crow = C + (size_t)row * N + colBase + tx * 8;
#pragma unroll
        for (int j4 = 0; j4 < 8; j4 += 4) {
            const int col = colBase + tx * 8 + j4;
            if (col < N) {
                float4 v;
                float x0 = acc[i][j4 + 0], x1 = acc[i][j4 + 1];
                float x2 = acc[i][j4 + 2], x3 = acc[i][j4 + 3];
                if (OP == 1) { x0 = siluf(x0); x1 = siluf(x1); x2 = siluf(x2); x3 = siluf(x3); }
                v.x = x0; v.y = x1; v.z = x2; v.w = x3;
                *(float4*)(Crow + j4) = v;
            }
        }
    }
}

// ---------------------------------------------------------------------------
// beta / g kernel (unchanged)
// ---------------------------------------------------------------------------
__global__ __launch_bounds__(256) void bg_kernel(const float* __restrict__ hs,
                                                 const float* __restrict__ Wb,
                                                 const float* __restrict__ Wa,
                                                 const float* __restrict__ A_log,
                                                 const float* __restrict__ dt_bias,
                                                 float* __restrict__ beta,
                                                 float* __restrict__ g) {
    const int gw = (blockIdx.x * 256 + threadIdx.x) >> 6;
    const int lane = threadIdx.x & 63;
    if (gw >= T * 24) return;
    const int t = gw / 24, j = gw % 24;
    const float* W = (j < 12) ? (Wb + j) : (Wa + (j - 12));
    float s = 0.0f;
    for (int kk = lane; kk < HID; kk += 64)
        s += hs[(size_t)t * HID + kk] * W[(size_t)kk * NH];
    s += __shfl_xor(s, 1);  s += __shfl_xor(s, 2);  s += __shfl_xor(s, 4);
    s += __shfl_xor(s, 8);  s += __shfl_xor(s, 16); s += __shfl_xor(s, 32);
    if (lane == 0) {
        if (j < 12) {
            beta[t * NH + j] = 1.0f / (1.0f + __expf(-s));
        } else {
            const int hh = j - 12;
            const float x = s + dt_bias[hh];
            const float sp = (x > 20.0f) ? x : log1pf(__expf(x));
            g[t * NH + hh] = -__expf(A_log[hh]) * sp;
        }
    }
}

// ---------------------------------------------------------------------------
// Dynamic causal conv (unchanged)
// ---------------------------------------------------------------------------
__global__ __launch_bounds__(256) void conv_kernel(const float* __restrict__ vpre,
                                                   const float* __restrict__ w,
                                                   float* __restrict__ v) {
    const int idx = blockIdx.x * 256 + threadIdx.x;
    if (idx >= T * HID) return;
    const int t = idx / HID, d = idx % HID;
    const float4 wv = *(const float4*)(w + (size_t)t * (HID * CONVK) + d * 4);
    const float w4[4] = { wv.x, wv.y, wv.z, wv.w };
    float acc = 0.0f;
#pragma unroll
    for (int i = 0; i < CONVK; i++) {
        const int ts = t - (CONVK - 1) + i;
        if (ts >= 0) acc += vpre[(size_t)ts * HID + d] * w4[i];
    }
    v[idx] = siluf(acc);
}

// ---------------------------------------------------------------------------
// D1: chunk-local WY precompute, all fp32. grid (NC, NH), 256 threads.
// A[i][j] = beta_i*exp(cs_i-cs_j)*(k_i.k_j), j<i.
// Solve (I+A)[X1|X2] = [beta*V | beta*exp(cs)*K].
// M[i][j] = exp(cs_i-cs_j)*(q_i.k_j), j<=i  (fp32 out).
// ---------------------------------------------------------------------------
__global__ __launch_bounds__(256) void chunkloc_kernel(
    const float* __restrict__ q, const float* __restrict__ k, const float* __restrict__ v,
    const float* __restrict__ g, const float* __restrict__ beta,
    float* __restrict__ X1g, float* __restrict__ X2g,
    float* __restrict__ Mg, float* __restrict__ csg)
{
    __shared__ float KT[128 * 68];    // K^T, resident whole kernel
    __shared__ float buf2[128 * 68];  // V (64x132) then Q^T (128x68)
    __shared__ float As[64 * 68];
    __shared__ float cs[64], sb[64], sbb[64];

    const int c = blockIdx.x, h = blockIdx.y;
    const int tid = threadIdx.x;
    const size_t rowbase = (size_t)(c * CH) * HID + h * DK;

    // stage K transposed: KT[d*68 + i] = k[c*64+i][h*128+d]
    {
        const int i = tid >> 2, dq = tid & 3;
        const float* src = k + rowbase + (size_t)i * HID + dq * 32;
        for (int f = 0; f < 8; ++f) {
            float4 x = *(const float4*)(src + f * 4);
            int d = dq * 32 + f * 4;
            KT[(d + 0) * 68 + i] = x.x; KT[(d + 1) * 68 + i] = x.y;
            KT[(d + 2) * 68 + i] = x.z; KT[(d + 3) * 68 + i] = x.w;
        }
    }
    if (tid < 64) {   // wave 0: load g/beta, prefix-sum cs
        float gv = g[(c * CH + tid) * NH + h];
        float bv = beta[(c * CH + tid) * NH + h];
        float csv = gv;
#pragma unroll
        for (int off = 1; off < 64; off <<= 1) {
            float n = __shfl_up(csv, off);
            if (tid >= off) csv += n;
        }
        cs[tid] = csv; sb[tid] = bv; sbb[tid] = bv * __expf(csv);
    }
    __syncthreads();

    // A phase: 16x16 thread tiles of 4x4
    {
        const int ti = tid & 15, tj = tid >> 4;
        const int j0 = ti * 4, i0 = tj * 4;
        float acc[4][4] = {{0}};
        for (int d = 0; d < 128; ++d) {
            float4 av = *(const float4*)&KT[d * 68 + i0];
            float4 bv = *(const float4*)&KT[d * 68 + j0];
            const float ap[4] = {av.x, av.y, av.z, av.w};
            const float bp[4] = {bv.x, bv.y, bv.z, bv.w};
#pragma unroll
            for (int r = 0; r < 4; ++r)
#pragma unroll
                for (int s = 0; s < 4; ++s) acc[r][s] += ap[r] * bp[s];
        }
#pragma unroll
        for (int r = 0; r < 4; ++r)
#pragma unroll
            for (int s = 0; s < 4; ++s) {
                int i = i0 + r, j = j0 + s;
                As[i * 68 + j] = (j < i) ? sb[i] * __expf(cs[i] - cs[j]) * acc[r][s] : 0.0f;
            }
    }

    // X2 RHS from resident KT
    float xc[64];
    const int col = tid;
    if (col >= 128) {
        const int dcol = col - 128;
#pragma unroll
        for (int i4 = 0; i4 < 16; ++i4) {
            float4 kq = *(const float4*)&KT[dcol * 68 + i4 * 4];
            xc[i4 * 4 + 0] = sbb[i4 * 4 + 0] * kq.x;
            xc[i4 * 4 + 1] = sbb[i4 * 4 + 1] * kq.y;
            xc[i4 * 4 + 2] = sbb[i4 * 4 + 2] * kq.z;
            xc[i4 * 4 + 3] = sbb[i4 * 4 + 3] * kq.w;
        }
    }

    // stage V row-major into buf2 (64 x 132)
    {
        const int i = tid >> 2, cq = tid & 3;
        const float* src = v + (size_t)(c * CH + i) * HID + h * DV + cq * 32;
        for (int f = 0; f < 8; ++f)
            *(float4*)&buf2[i * 132 + cq * 32 + f * 4] = *(const float4*)(src + f * 4);
    }
    __syncthreads();   // As complete + V complete

    if (col < 128) {
#pragma unroll
        for (int i = 0; i < 64; ++i) xc[i] = sb[i] * buf2[i * 132 + col];
    }

    // forward substitution, column in registers
#pragma unroll
    for (int i = 1; i < 64; ++i) {
        float a = xc[i];
#pragma unroll
        for (int j4 = 0; j4 < (i + 3) / 4; ++j4) {
            float4 a4 = *(const float4*)&As[i * 68 + j4 * 4];
            a -= a4.x * xc[j4 * 4 + 0] + a4.y * xc[j4 * 4 + 1]
               + a4.z * xc[j4 * 4 + 2] + a4.w * xc[j4 * 4 + 3];
        }
        xc[i] = a;
    }

    // store X1/X2 (coalesced over col)
    {
        const size_t xbase = (size_t)(h * NC + c) * CH * 128;
        if (col < 128) {
            for (int i = 0; i < 64; ++i) X1g[xbase + (size_t)i * 128 + col] = xc[i];
        } else {
            for (int i = 0; i < 64; ++i) X2g[xbase + (size_t)i * 128 + (col - 128)] = xc[i];
        }
    }
    __syncthreads();   // V reads done before overwrite

    // stage Q^T into buf2
    {
        const int i = tid >> 2, dq = tid & 3;
        const float* qsrc = q + rowbase + (size_t)i * HID + dq * 32;
        for (int f = 0; f < 8; ++f) {
            float4 x = *(const float4*)(qsrc + f * 4);
            int d = dq * 32 + f * 4;
            buf2[(d + 0) * 68 + i] = x.x; buf2[(d + 1) * 68 + i] = x.y;
            buf2[(d + 2) * 68 + i] = x.z; buf2[(d + 3) * 68 + i] = x.w;
        }
    }
    __syncthreads();

    // M phase (fp32 in/out)
    {
        const int ti = tid & 15, tj = tid >> 4;
        const int j0 = ti * 4, i0 = tj * 4;
        float acc[4][4] = {{0}};
        for (int d = 0; d < 128; ++d) {
            float4 qv = *(const float4*)&buf2[d * 68 + i0];
            float4 kv = *(const float4*)&KT[d * 68 + j0];
            const float ap[4] = {qv.x, qv.y, qv.z, qv.w};
            const float bp[4] = {kv.x, kv.y, kv.z, kv.w};
#pragma unroll
            for (int r = 0; r < 4; ++r)
#pragma unroll
                for (int s = 0; s < 4; ++s) acc[r][s] += ap[r] * bp[s];
        }
        const size_t mbase = (size_t)(h * NC + c) * CH * CH;
#pragma unroll
        for (int r = 0; r < 4; ++r)
#pragma unroll
            for (int s = 0; s < 4; ++s) {
                int i = i0 + r, j = j0 + s;
                Mg[mbase + (size_t)i * 64 + j] =
                    (j <= i) ? __expf(cs[i] - cs[j]) * acc[r][s] : 0.0f;
            }
    }
    if (tid < 64) csg[(size_t)(h * NC + c) * CH + tid] = cs[tid];
}

// ---------------------------------------------------------------------------
// D2: serial inter-chunk recurrence, all fp32. grid (NH, 8): head x dv-slice.
// Per chunk:  U = X1 - X2 S   (write U in-place over X1)
//             o_qs = exp(cs_i) * q_i . S      (unscaled; D3 adds M U + scale)
//             S = exp(cs_63) S + K'^T U,  K'_i = exp(cs_63 - cs_i) k_i
// ---------------------------------------------------------------------------
__global__ __launch_bounds__(256) void state_kernel(
    const float* __restrict__ k, const float* __restrict__ q,
    float* __restrict__ X1g /* in: X1, out: U */,
    const float* __restrict__ X2g, const float* __restrict__ csg,
    float* __restrict__ o)
{
    __shared__ float buf[64 * 132];   // X2 -> Q -> K' tiles
    __shared__ float St[16 * 132];    // S^T slice: [dv_local][dk]
    __shared__ float Ut[16 * 68];     // U^T slice: [dv_local][i]
    __shared__ float scs[64];

    const int h = blockIdx.x, db = blockIdx.y;
    const int tid = threadIdx.x;
    const int cL = tid & 15, grp = tid >> 4;
    const int i0 = grp * 4;

    for (int idx = tid; idx < 16 * 132; idx += 256) St[idx] = 0.0f;
    __syncthreads();

    for (int c = 0; c < NC; ++c) {
        const size_t hc = (size_t)(h * NC + c);
        const size_t xb = hc * CH * 128;
        if (tid < 64) scs[tid] = csg[hc * CH + tid];
        // stage X2 tile
        {
            const int i = tid >> 2, q4 = tid & 3;
            const float* src = X2g + xb + (size_t)i * 128 + q4 * 32;
            for (int f = 0; f < 8; ++f)
                *(float4*)&buf[i * 132 + q4 * 32 + f * 4] = *(const float4*)(src + f * 4);
        }
        __syncthreads();

        // U = X1 - X2 S ; store to Ut (LDS) and in-place to X1g (global)
        {
            float acc[4];
#pragma unroll
            for (int r = 0; r < 4; ++r)
                acc[r] = X1g[xb + (size_t)(i0 + r) * 128 + db * 16 + cL];
            for (int d4 = 0; d4 < 32; ++d4) {
                float4 s4 = *(const float4*)&St[cL * 132 + d4 * 4];
#pragma unroll
                for (int r = 0; r < 4; ++r) {
                    float4 x4 = *(const float4*)&buf[(i0 + r) * 132 + d4 * 4];
                    acc[r] -= x4.x * s4.x + x4.y * s4.y + x4.z * s4.z + x4.w * s4.w;
                }
            }
#pragma unroll
            for (int r = 0; r < 4; ++r) {
                Ut[cL * 68 + i0 + r] = acc[r];
                X1g[xb + (size_t)(i0 + r) * 128 + db * 16 + cL] = acc[r];
            }
        }
        __syncthreads();

        // stage Q tile
        {
            const int i = tid >> 2, q4 = tid & 3;
            const float* src = q + (size_t)(c * CH + i) * HID + h * DK + q4 * 32;
            for (int f = 0; f < 8; ++f)
                *(float4*)&buf[i * 132 + q4 * 32 + f * 4] = *(const float4*)(src + f * 4);
        }
        __syncthreads();

        // o_qs = exp(cs_i) * Q . S  (uses pre-update S)
        {
            float acc[4] = {0.f, 0.f, 0.f, 0.f};
            for (int d4 = 0; d4 < 32; ++d4) {
                float4 s4 = *(const float4*)&St[cL * 132 + d4 * 4];
#pragma unroll
                for (int r = 0; r < 4; ++r) {
                    float4 x4 = *(const float4*)&buf[(i0 + r) * 132 + d4 * 4];
                    acc[r] += x4.x * s4.x + x4.y * s4.y + x4.z * s4.z + x4.w * s4.w;
                }
            }
#pragma unroll
            for (int r = 0; r < 4; ++r)
                o[(size_t)(c * CH + i0 + r) * HID + h * DV + db * 16 + cL] =
                    __expf(scs[i0 + r]) * acc[r];
        }
        __syncthreads();

        // stage K' = exp(cs63-cs_i) * k_i
        {
            const int i = tid >> 2, q4 = tid & 3;
            const float dec = __expf(scs[63] - scs[i]);
            const float* src = k + (size_t)(c * CH + i) * HID + h * DK + q4 * 32;
            for (int f = 0; f < 8; ++f) {
                float4 x = *(const float4*)(src + f * 4);
                x.x *= dec; x.y *= dec; x.z *= dec; x.w *= dec;
                *(float4*)&buf[i * 132 + q4 * 32 + f * 4] = x;
            }
        }
        __syncthreads();

        // S = bC*S + K'^T U
        {
            const int dk0 = grp * 8;
            const float bC = __expf(scs[63]);
            float acc[8];
#pragma unroll
            for (int e = 0; e < 8; ++e) acc[e] = bC * St[cL * 132 + dk0 + e];
            for (int i4 = 0; i4 < 16; ++i4) {
                float4 u4 = *(const float4*)&Ut[cL * 68 + i4 * 4];
                const float uu[4] = {u4.x, u4.y, u4.z, u4.w};
#pragma unroll
                for (int s = 0; s < 4; ++s) {
                    const float* kr = &buf[(i4 * 4 + s) * 132 + dk0];
#pragma unroll
                    for (int e = 0; e < 8; ++e) acc[e] += uu[s] * kr[e];
                }
            }
#pragma unroll
            for (int e = 0; e < 8; ++e) St[cL * 132 + dk0 + e] = acc[e];
        }
        __syncthreads();
    }
}

// ---------------------------------------------------------------------------
// D3: o = scale * (o + M U). grid (NC, NH, 2): dv-half per block. All fp32.
// ---------------------------------------------------------------------------
__global__ __launch_bounds__(256) void outk_kernel(
    const float* __restrict__ Ug, const float* __restrict__ Mg,
    float* __restrict__ o)
{
    __shared__ float Msh[64 * 68];
    __shared__ float Ush[64 * 68];

    const int c = blockIdx.x, h = blockIdx.y;
    const int dvb = blockIdx.z * 64;
    const int tid = threadIdx.x;
    const size_t hc = (size_t)(h * NC + c);

    for (int e = 0; e < 16; ++e) {
        int idx = e * 256 + tid;              // 4096 = 64 x 64
        Msh[(idx >> 6) * 68 + (idx & 63)] = Mg[hc * CH * CH + idx];
    }
    for (int e = 0; e < 16; ++e) {
        int idx = e * 256 + tid;
        int j = idx >> 6, cc = idx & 63;
        Ush[j * 68 + cc] = Ug[hc * CH * 128 + (size_t)j * 128 + dvb + cc];
    }
    __syncthreads();

    const int tx = tid & 15, ty = tid >> 4;
    const int c0 = tx * 4, i0 = ty * 4;
    float acc[4][4] = {{0}};
    for (int j4 = 0; j4 < 16; ++j4) {
        float uv[4][4];
#pragma unroll
        for (int s = 0; s < 4; ++s) {
            float4 u4 = *(const float4*)&Ush[(j4 * 4 + s) * 68 + c0];
            uv[s][0] = u4.x; uv[s][1] = u4.y; uv[s][2] = u4.z; uv[s][3] = u4.w;
        }
#pragma unroll
        for (int r = 0; r < 4; ++r) {
            float4 m4 = *(const float4*)&Msh[(i0 + r) * 68 + j4 * 4];
            const float mv[4] = {m4.x, m4.y, m4.z, m4.w};
#pragma unroll
            for (int s = 0; s < 4; ++s)
#pragma unroll
                for (int e = 0; e < 4; ++e) acc[r][e] += mv[s] * uv[s][e];
        }
    }
    const float scale = 0.08838834764831845f;
#pragma unroll
    for (int r = 0; r < 4; ++r) {
        float* op = &o[(size_t)(c * CH + i0 + r) * HID + h * DV + dvb + c0];
        float4 prev = *(const float4*)op;
        float4 ov = make_float4(scale * (prev.x + acc[r][0]),
                                scale * (prev.y + acc[r][1]),
                                scale * (prev.z + acc[r][2]),
                                scale * (prev.w + acc[r][3]));
        *(float4*)op = ov;
    }
}

// ---------------------------------------------------------------------------
// Gated RMSNorm (unchanged)
// ---------------------------------------------------------------------------
__global__ __launch_bounds__(256) void normgate_kernel(const float* __restrict__ o,
                                                       const float* __restrict__ gsil,
                                                       const float* __restrict__ nw,
                                                       float* __restrict__ out) {
    const int gw = (blockIdx.x * 256 + threadIdx.x) >> 6;
    const int lane = threadIdx.x & 63;
    if (gw >= T * NH) return;
    const int t = gw / NH, h = gw % NH;
    const size_t base = (size_t)t * HID + h * DV;
    const float a = o[base + lane];
    const float b = o[base + lane + 64];
    float ss = a * a + b * b;
    ss += __shfl_xor(ss, 1);  ss += __shfl_xor(ss, 2);  ss += __shfl_xor(ss, 4);
    ss += __shfl_xor(ss, 8);  ss += __shfl_xor(ss, 16); ss += __shfl_xor(ss, 32);
    const float r = rsqrtf(ss * (1.0f / 128.0f) + 1e-5f);
    out[base + lane]      = a * r * nw[lane]      * gsil[base + lane];
    out[base + lane + 64] = b * r * nw[lane + 64] * gsil[base + lane + 64];
}

// ---------------------------------------------------------------------------
extern "C" void kernel_launch(void* const* d_in, const int* in_sizes, int n_in,
                              void* d_out, int out_size, void* d_ws, size_t ws_size,
                              hipStream_t stream) {
    const float* hs      = (const float*)d_in[0];
    const float* Wq      = (const float*)d_in[1];
    const float* Wk      = (const float*)d_in[2];
    const float* Wv      = (const float*)d_in[3];
    const float* Wb      = (const float*)d_in[4];
    const float* Wa      = (const float*)d_in[5];
    const float* A_log   = (const float*)d_in[6];
    const float* dt_bias = (const float*)d_in[7];
    const float* Wg1     = (const float*)d_in[8];
    const float* Wg2     = (const float*)d_in[9];
    const float* Wgate   = (const float*)d_in[10];
    const float* norm_w  = (const float*)d_in[11];
    const float* Wo      = (const float*)d_in[12];

    float* ws = (float*)d_ws;
    // total footprint 25,608,192 floats = 102.4 MB (same as passing round 1)
    float* q    = ws;                      // live till D2
    float* kbuf = ws + 3145728;            // live till D2; then onorm
    float* vpre = ws + 6291456;            // gsil aliases after conv
    float* vbuf = ws + 9437184;            // live till D1; then o
    float* w1   = ws + 12582912;
    float* wcv  = ws + 12976128;           // conv weights; region reused after conv:
    float* X1g  = ws + 12976128;           // 3,145,728 (becomes U in-place in D2)
    float* X2g  = ws + 16121856;           // 3,145,728
    float* Mg   = ws + 19267584;           // 1,572,864 fp32
    float* csg  = ws + 20840448;           // 24,576
    float* beta = ws + 25559040;
    float* g    = ws + 25583616;
    float* gsil = vpre;
    float* o    = vbuf;
    float* onorm= kbuf;

    const dim3 blk(256);
    const dim3 gBig(12, 16);

    sgemm<1><<<gBig, blk, 0, stream>>>(hs, Wq, q,    2048, 1536, 1536);
    sgemm<1><<<gBig, blk, 0, stream>>>(hs, Wk, kbuf, 2048, 1536, 1536);
    sgemm<0><<<gBig, blk, 0, stream>>>(hs, Wv, vpre, 2048, 1536, 1536);
    sgemm<1><<<dim3(2, 16),  blk, 0, stream>>>(hs, Wg1, w1,  2048, 192, 1536);
    sgemm<0><<<dim3(48, 16), blk, 0, stream>>>(w1, Wg2, wcv, 2048, 6144, 192);
    bg_kernel<<<12288, blk, 0, stream>>>(hs, Wb, Wa, A_log, dt_bias, beta, g);
    conv_kernel<<<(T * HID) / 256, blk, 0, stream>>>(vpre, wcv, vbuf);
    sgemm<1><<<gBig, blk, 0, stream>>>(hs, Wgate, gsil, 2048, 1536, 1536);

    chunkloc_kernel<<<dim3(NC, NH), blk, 0, stream>>>(q, kbuf, vbuf, g, beta,
                                                      X1g, X2g, Mg, csg);
    state_kernel<<<dim3(NH, 8), blk, 0, stream>>>(kbuf, q, X1g, X2g, csg, o);
    outk_kernel<<<dim3(NC, NH, 2), blk, 0, stream>>>(X1g, Mg, o);

    normgate_kernel<<<6144, blk, 0, stream>>>(o, gsil, norm_w, onorm);
    sgemm<0><<<gBig, blk, 0, stream>>>(onorm, Wo, (float*)d_out, 2048, 1536, 1536);
}

// Round 5
// 981.002 us; speedup vs baseline: 3.6874x; 2.5461x over previous
//
#include <hip/hip_runtime.h>
#include <hip/hip_bf16.h>
#include <math.h>

#define T     2048
#define HID   1536
#define NH    12
#define DK    128
#define DV    128
#define CONVK 4
#define CH    64
#define NC    32

typedef __attribute__((ext_vector_type(8))) short bf16x8;
typedef __attribute__((ext_vector_type(4))) float floatx4;

__device__ __forceinline__ float siluf(float x) {
    return x / (1.0f + __expf(-x));
}
__device__ __forceinline__ unsigned short f2bf(float f) {
    union { __hip_bfloat16 b; unsigned short u; } cv;
    cv.b = __float2bfloat16(f);
    return cv.u;
}
__device__ __forceinline__ float bf2f(unsigned short u) {
    union { unsigned int u; float f; } cv;
    cv.u = ((unsigned int)u) << 16;
    return cv.f;
}
__device__ __forceinline__ void gl_lds16(const void* g, void* l) {
    __builtin_amdgcn_global_load_lds(
        (const __attribute__((address_space(1))) void*)g,
        (__attribute__((address_space(3))) void*)l, 16, 0, 0);
}

// ---------------------------------------------------------------------------
// split fp32 -> (hi, lo) bf16 pair, vectorized x4
// ---------------------------------------------------------------------------
__global__ __launch_bounds__(256) void splitcast_kernel(const float* __restrict__ s,
                                                        unsigned short* __restrict__ hi,
                                                        unsigned short* __restrict__ lo,
                                                        int n4) {
    int i = blockIdx.x * 256 + threadIdx.x;
    if (i >= n4) return;
    float4 x = ((const float4*)s)[i];
    ushort4 h, l;
    h.x = f2bf(x.x); l.x = f2bf(x.x - bf2f(h.x));
    h.y = f2bf(x.y); l.y = f2bf(x.y - bf2f(h.y));
    h.z = f2bf(x.z); l.z = f2bf(x.z - bf2f(h.z));
    h.w = f2bf(x.w); l.w = f2bf(x.w - bf2f(h.w));
    ((ushort4*)hi)[i] = h;
    ((ushort4*)lo)[i] = l;
}

// ---------------------------------------------------------------------------
// transpose + split: src (K x N fp32) -> hi/lo (N x K bf16). K%32==0.
// block (32,8), grid (ceil(N/32), K/32)
// ---------------------------------------------------------------------------
__global__ __launch_bounds__(256) void transsplit_kernel(const float* __restrict__ src,
                                                         unsigned short* __restrict__ hi,
                                                         unsigned short* __restrict__ lo,
                                                         int K, int N) {
    __shared__ float tile[32][33];
    const int k0 = blockIdx.y * 32, n0 = blockIdx.x * 32;
    const int tx = threadIdx.x, ty = threadIdx.y;
#pragma unroll
    for (int r = 0; r < 4; ++r) {
        int kk = k0 + ty + 8 * r, nn = n0 + tx;
        tile[ty + 8 * r][tx] = (nn < N) ? src[(size_t)kk * N + nn] : 0.0f;
    }
    __syncthreads();
#pragma unroll
    for (int r = 0; r < 4; ++r) {
        int nn = n0 + ty + 8 * r, kk = k0 + tx;
        if (nn < N) {
            float x = tile[tx][ty + 8 * r];
            unsigned short h = f2bf(x);
            hi[(size_t)nn * K + kk] = h;
            lo[(size_t)nn * K + kk] = f2bf(x - bf2f(h));
        }
    }
}

// ---------------------------------------------------------------------------
// Split-bf16 MFMA GEMM (effectively fp32): C = (Ah+Al)(Bh+Bl)^T, lo*lo dropped.
// 128x128 tile, BK=32, 256 thr. A: M x K, B: N x K (both hi/lo bf16 row-major).
// EPI 0: C fp32.  EPI 1: q|k|v routing.  EPI 2: gate|w1|bg routing.  EPI 3: Cb bf16.
// ---------------------------------------------------------------------------
template<int EPI>
__global__ __launch_bounds__(256)
void mgemm(const unsigned short* __restrict__ Ah, const unsigned short* __restrict__ Al,
           const unsigned short* __restrict__ Bh, const unsigned short* __restrict__ Bl,
           int K, int N, float* __restrict__ C, unsigned short* __restrict__ Cb,
           float* __restrict__ qf, float* __restrict__ kf, float* __restrict__ vf,
           unsigned short* __restrict__ gsilb, float* __restrict__ w1f,
           float* __restrict__ bgraw)
{
    __shared__ unsigned short AsH[4096], AsL[4096], BsH[4096], BsL[4096];
    const int tid = threadIdx.x;
    const int wave = tid >> 6, lane = tid & 63;
    const int wr = wave >> 1, wc = wave & 1;
    const int lm = lane & 15, lq = lane >> 4;
    const int rowBase = blockIdx.y * 128, colBase = blockIdx.x * 128;

    floatx4 acc[4][4];
#pragma unroll
    for (int i = 0; i < 4; ++i)
#pragma unroll
        for (int j = 0; j < 4; ++j) acc[i][j] = (floatx4){0.f, 0.f, 0.f, 0.f};

    const int mt0 = wave * 2, mt1 = wave * 2 + 1;
    const size_t aOff0 = (size_t)(rowBase + mt0 * 16 + lm) * K + lq * 8;
    const size_t aOff1 = (size_t)(rowBase + mt1 * 16 + lm) * K + lq * 8;
    const size_t bOff0 = (size_t)(colBase + mt0 * 16 + lm) * K + lq * 8;
    const size_t bOff1 = (size_t)(colBase + mt1 * 16 + lm) * K + lq * 8;

    for (int k0 = 0; k0 < K; k0 += 32) {
        gl_lds16(Ah + aOff0 + k0, &AsH[mt0 * 512]);
        gl_lds16(Ah + aOff1 + k0, &AsH[mt1 * 512]);
        gl_lds16(Al + aOff0 + k0, &AsL[mt0 * 512]);
        gl_lds16(Al + aOff1 + k0, &AsL[mt1 * 512]);
        gl_lds16(Bh + bOff0 + k0, &BsH[mt0 * 512]);
        gl_lds16(Bh + bOff1 + k0, &BsH[mt1 * 512]);
        gl_lds16(Bl + bOff0 + k0, &BsL[mt0 * 512]);
        gl_lds16(Bl + bOff1 + k0, &BsL[mt1 * 512]);
        __syncthreads();
        bf16x8 ah[4], al[4], bh[4], bl[4];
#pragma unroll
        for (int i = 0; i < 4; ++i) {
            ah[i] = *(const bf16x8*)&AsH[(wr * 4 + i) * 512 + lane * 8];
            al[i] = *(const bf16x8*)&AsL[(wr * 4 + i) * 512 + lane * 8];
            bh[i] = *(const bf16x8*)&BsH[(wc * 4 + i) * 512 + lane * 8];
            bl[i] = *(const bf16x8*)&BsL[(wc * 4 + i) * 512 + lane * 8];
        }
#pragma unroll
        for (int mi = 0; mi < 4; ++mi)
#pragma unroll
            for (int ni = 0; ni < 4; ++ni) {
                acc[mi][ni] = __builtin_amdgcn_mfma_f32_16x16x32_bf16(
                    ah[mi], bh[ni], acc[mi][ni], 0, 0, 0);
                acc[mi][ni] = __builtin_amdgcn_mfma_f32_16x16x32_bf16(
                    ah[mi], bl[ni], acc[mi][ni], 0, 0, 0);
                acc[mi][ni] = __builtin_amdgcn_mfma_f32_16x16x32_bf16(
                    al[mi], bh[ni], acc[mi][ni], 0, 0, 0);
            }
        __syncthreads();
    }

#pragma unroll
    for (int mi = 0; mi < 4; ++mi)
#pragma unroll
        for (int ni = 0; ni < 4; ++ni) {
            const int col = colBase + wc * 64 + ni * 16 + lm;
#pragma unroll
            for (int r = 0; r < 4; ++r) {
                const int row = rowBase + wr * 64 + mi * 16 + lq * 4 + r;
                const float x = acc[mi][ni][r];
                if (EPI == 0) {
                    C[(size_t)row * N + col] = x;
                } else if (EPI == 3) {
                    Cb[(size_t)row * N + col] = f2bf(x);
                } else if (EPI == 1) {
                    if (col < 1536)       qf[(size_t)row * 1536 + col] = siluf(x);
                    else if (col < 3072)  kf[(size_t)row * 1536 + col - 1536] = siluf(x);
                    else                  vf[(size_t)row * 1536 + col - 3072] = x;
                } else {  // EPI == 2
                    if (col < 1536)       gsilb[(size_t)row * 1536 + col] = f2bf(siluf(x));
                    else if (col < 1728)  w1f[(size_t)row * 192 + col - 1536] = siluf(x);
                    else if (col < 1752)  bgraw[(size_t)row * 24 + col - 1728] = x;
                }
            }
        }
}

// ---------------------------------------------------------------------------
// beta/g from raw fused-GEMM scores
// ---------------------------------------------------------------------------
__global__ __launch_bounds__(256) void bg2_kernel(const float* __restrict__ bgraw,
                                                  const float* __restrict__ A_log,
                                                  const float* __restrict__ dt_bias,
                                                  float* __restrict__ beta,
                                                  float* __restrict__ g) {
    int idx = blockIdx.x * 256 + threadIdx.x;
    if (idx >= T * 24) return;
    int t = idx / 24, c = idx % 24;
    float x = bgraw[idx];
    if (c < 12) {
        beta[t * NH + c] = 1.0f / (1.0f + __expf(-x));
    } else {
        int h = c - 12;
        float y = x + dt_bias[h];
        float sp = (y > 20.0f) ? y : log1pf(__expf(y));
        g[t * NH + h] = -__expf(A_log[h]) * sp;
    }
}

// ---------------------------------------------------------------------------
// Dynamic causal conv; weights bf16, activations fp32
// ---------------------------------------------------------------------------
__global__ __launch_bounds__(256) void conv_kernel(const float* __restrict__ vpre,
                                                   const unsigned short* __restrict__ w,
                                                   float* __restrict__ v) {
    const int idx = blockIdx.x * 256 + threadIdx.x;
    if (idx >= T * HID) return;
    const int t = idx / HID, d = idx % HID;
    const ushort4 wv = *(const ushort4*)(w + (size_t)t * (HID * CONVK) + d * 4);
    const float w4[4] = { bf2f(wv.x), bf2f(wv.y), bf2f(wv.z), bf2f(wv.w) };
    float acc = 0.0f;
#pragma unroll
    for (int i = 0; i < CONVK; i++) {
        const int ts = t - (CONVK - 1) + i;
        if (ts >= 0) acc += vpre[(size_t)ts * HID + d] * w4[i];
    }
    v[idx] = siluf(acc);
}

// ---------------------------------------------------------------------------
// D1: chunk-local WY precompute, all fp32 (round-3 verified version)
// ---------------------------------------------------------------------------
__global__ __launch_bounds__(256) void chunkloc_kernel(
    const float* __restrict__ q, const float* __restrict__ k, const float* __restrict__ v,
    const float* __restrict__ g, const float* __restrict__ beta,
    float* __restrict__ X1g, float* __restrict__ X2g,
    float* __restrict__ Mg, float* __restrict__ csg)
{
    __shared__ float KT[128 * 68];
    __shared__ float buf2[128 * 68];
    __shared__ float As[64 * 68];
    __shared__ float cs[64], sb[64], sbb[64];

    const int c = blockIdx.x, h = blockIdx.y;
    const int tid = threadIdx.x;
    const size_t rowbase = (size_t)(c * CH) * HID + h * DK;

    {
        const int i = tid >> 2, dq = tid & 3;
        const float* src = k + rowbase + (size_t)i * HID + dq * 32;
        for (int f = 0; f < 8; ++f) {
            float4 x = *(const float4*)(src + f * 4);
            int d = dq * 32 + f * 4;
            KT[(d + 0) * 68 + i] = x.x; KT[(d + 1) * 68 + i] = x.y;
            KT[(d + 2) * 68 + i] = x.z; KT[(d + 3) * 68 + i] = x.w;
        }
    }
    if (tid < 64) {
        float gv = g[(c * CH + tid) * NH + h];
        float bv = beta[(c * CH + tid) * NH + h];
        float csv = gv;
#pragma unroll
        for (int off = 1; off < 64; off <<= 1) {
            float n = __shfl_up(csv, off);
            if (tid >= off) csv += n;
        }
        cs[tid] = csv; sb[tid] = bv; sbb[tid] = bv * __expf(csv);
    }
    __syncthreads();

    {
        const int ti = tid & 15, tj = tid >> 4;
        const int j0 = ti * 4, i0 = tj * 4;
        float acc[4][4] = {{0}};
        for (int d = 0; d < 128; ++d) {
            float4 av = *(const float4*)&KT[d * 68 + i0];
            float4 bv = *(const float4*)&KT[d * 68 + j0];
            const float ap[4] = {av.x, av.y, av.z, av.w};
            const float bp[4] = {bv.x, bv.y, bv.z, bv.w};
#pragma unroll
            for (int r = 0; r < 4; ++r)
#pragma unroll
                for (int s = 0; s < 4; ++s) acc[r][s] += ap[r] * bp[s];
        }
#pragma unroll
        for (int r = 0; r < 4; ++r)
#pragma unroll
            for (int s = 0; s < 4; ++s) {
                int i = i0 + r, j = j0 + s;
                As[i * 68 + j] = (j < i) ? sb[i] * __expf(cs[i] - cs[j]) * acc[r][s] : 0.0f;
            }
    }

    float xc[64];
    const int col = tid;
    if (col >= 128) {
        const int dcol = col - 128;
#pragma unroll
        for (int i4 = 0; i4 < 16; ++i4) {
            float4 kq = *(const float4*)&KT[dcol * 68 + i4 * 4];
            xc[i4 * 4 + 0] = sbb[i4 * 4 + 0] * kq.x;
            xc[i4 * 4 + 1] = sbb[i4 * 4 + 1] * kq.y;
            xc[i4 * 4 + 2] = sbb[i4 * 4 + 2] * kq.z;
            xc[i4 * 4 + 3] = sbb[i4 * 4 + 3] * kq.w;
        }
    }

    {
        const int i = tid >> 2, cq = tid & 3;
        const float* src = v + (size_t)(c * CH + i) * HID + h * DV + cq * 32;
        for (int f = 0; f < 8; ++f)
            *(float4*)&buf2[i * 132 + cq * 32 + f * 4] = *(const float4*)(src + f * 4);
    }
    __syncthreads();

    if (col < 128) {
#pragma unroll
        for (int i = 0; i < 64; ++i) xc[i] = sb[i] * buf2[i * 132 + col];
    }

#pragma unroll
    for (int i = 1; i < 64; ++i) {
        float a = xc[i];
#pragma unroll
        for (int j4 = 0; j4 < (i + 3) / 4; ++j4) {
            float4 a4 = *(const float4*)&As[i * 68 + j4 * 4];
            a -= a4.x * xc[j4 * 4 + 0] + a4.y * xc[j4 * 4 + 1]
               + a4.z * xc[j4 * 4 + 2] + a4.w * xc[j4 * 4 + 3];
        }
        xc[i] = a;
    }

    {
        const size_t xbase = (size_t)(h * NC + c) * CH * 128;
        if (col < 128) {
            for (int i = 0; i < 64; ++i) X1g[xbase + (size_t)i * 128 + col] = xc[i];
        } else {
            for (int i = 0; i < 64; ++i) X2g[xbase + (size_t)i * 128 + (col - 128)] = xc[i];
        }
    }
    __syncthreads();

    {
        const int i = tid >> 2, dq = tid & 3;
        const float* qsrc = q + rowbase + (size_t)i * HID + dq * 32;
        for (int f = 0; f < 8; ++f) {
            float4 x = *(const float4*)(qsrc + f * 4);
            int d = dq * 32 + f * 4;
            buf2[(d + 0) * 68 + i] = x.x; buf2[(d + 1) * 68 + i] = x.y;
            buf2[(d + 2) * 68 + i] = x.z; buf2[(d + 3) * 68 + i] = x.w;
        }
    }
    __syncthreads();

    {
        const int ti = tid & 15, tj = tid >> 4;
        const int j0 = ti * 4, i0 = tj * 4;
        float acc[4][4] = {{0}};
        for (int d = 0; d < 128; ++d) {
            float4 qv = *(const float4*)&buf2[d * 68 + i0];
            float4 kv = *(const float4*)&KT[d * 68 + j0];
            const float ap[4] = {qv.x, qv.y, qv.z, qv.w};
            const float bp[4] = {kv.x, kv.y, kv.z, kv.w};
#pragma unroll
            for (int r = 0; r < 4; ++r)
#pragma unroll
                for (int s = 0; s < 4; ++s) acc[r][s] += ap[r] * bp[s];
        }
        const size_t mbase = (size_t)(h * NC + c) * CH * CH;
#pragma unroll
        for (int r = 0; r < 4; ++r)
#pragma unroll
            for (int s = 0; s < 4; ++s) {
                int i = i0 + r, j = j0 + s;
                Mg[mbase + (size_t)i * 64 + j] =
                    (j <= i) ? __expf(cs[i] - cs[j]) * acc[r][s] : 0.0f;
            }
    }
    if (tid < 64) csg[(size_t)(h * NC + c) * CH + tid] = cs[tid];
}

// ---------------------------------------------------------------------------
// D2: serial inter-chunk recurrence, all fp32 (round-3 verified version)
// ---------------------------------------------------------------------------
__global__ __launch_bounds__(256) void state_kernel(
    const float* __restrict__ k, const float* __restrict__ q,
    float* __restrict__ X1g, const float* __restrict__ X2g,
    const float* __restrict__ csg, float* __restrict__ o)
{
    __shared__ float buf[64 * 132];
    __shared__ float St[16 * 132];
    __shared__ float Ut[16 * 68];
    __shared__ float scs[64];

    const int h = blockIdx.x, db = blockIdx.y;
    const int tid = threadIdx.x;
    const int cL = tid & 15, grp = tid >> 4;
    const int i0 = grp * 4;

    for (int idx = tid; idx < 16 * 132; idx += 256) St[idx] = 0.0f;
    __syncthreads();

    for (int c = 0; c < NC; ++c) {
        const size_t hc = (size_t)(h * NC + c);
        const size_t xb = hc * CH * 128;
        if (tid < 64) scs[tid] = csg[hc * CH + tid];
        {
            const int i = tid >> 2, q4 = tid & 3;
            const float* src = X2g + xb + (size_t)i * 128 + q4 * 32;
            for (int f = 0; f < 8; ++f)
                *(float4*)&buf[i * 132 + q4 * 32 + f * 4] = *(const float4*)(src + f * 4);
        }
        __syncthreads();

        {
            float acc[4];
#pragma unroll
            for (int r = 0; r < 4; ++r)
                acc[r] = X1g[xb + (size_t)(i0 + r) * 128 + db * 16 + cL];
            for (int d4 = 0; d4 < 32; ++d4) {
                float4 s4 = *(const float4*)&St[cL * 132 + d4 * 4];
#pragma unroll
                for (int r = 0; r < 4; ++r) {
                    float4 x4 = *(const float4*)&buf[(i0 + r) * 132 + d4 * 4];
                    acc[r] -= x4.x * s4.x + x4.y * s4.y + x4.z * s4.z + x4.w * s4.w;
                }
            }
#pragma unroll
            for (int r = 0; r < 4; ++r) {
                Ut[cL * 68 + i0 + r] = acc[r];
                X1g[xb + (size_t)(i0 + r) * 128 + db * 16 + cL] = acc[r];
            }
        }
        __syncthreads();

        {
            const int i = tid >> 2, q4 = tid & 3;
            const float* src = q + (size_t)(c * CH + i) * HID + h * DK + q4 * 32;
            for (int f = 0; f < 8; ++f)
                *(float4*)&buf[i * 132 + q4 * 32 + f * 4] = *(const float4*)(src + f * 4);
        }
        __syncthreads();

        {
            float acc[4] = {0.f, 0.f, 0.f, 0.f};
            for (int d4 = 0; d4 < 32; ++d4) {
                float4 s4 = *(const float4*)&St[cL * 132 + d4 * 4];
#pragma unroll
                for (int r = 0; r < 4; ++r) {
                    float4 x4 = *(const float4*)&buf[(i0 + r) * 132 + d4 * 4];
                    acc[r] += x4.x * s4.x + x4.y * s4.y + x4.z * s4.z + x4.w * s4.w;
                }
            }
#pragma unroll
            for (int r = 0; r < 4; ++r)
                o[(size_t)(c * CH + i0 + r) * HID + h * DV + db * 16 + cL] =
                    __expf(scs[i0 + r]) * acc[r];
        }
        __syncthreads();

        {
            const int i = tid >> 2, q4 = tid & 3;
            const float dec = __expf(scs[63] - scs[i]);
            const float* src = k + (size_t)(c * CH + i) * HID + h * DK + q4 * 32;
            for (int f = 0; f < 8; ++f) {
                float4 x = *(const float4*)(src + f * 4);
                x.x *= dec; x.y *= dec; x.z *= dec; x.w *= dec;
                *(float4*)&buf[i * 132 + q4 * 32 + f * 4] = x;
            }
        }
        __syncthreads();

        {
            const int dk0 = grp * 8;
            const float bC = __expf(scs[63]);
            float acc[8];
#pragma unroll
            for (int e = 0; e < 8; ++e) acc[e] = bC * St[cL * 132 + dk0 + e];
            for (int i4 = 0; i4 < 16; ++i4) {
                float4 u4 = *(const float4*)&Ut[cL * 68 + i4 * 4];
                const float uu[4] = {u4.x, u4.y, u4.z, u4.w};
#pragma unroll
                for (int s = 0; s < 4; ++s) {
                    const float* kr = &buf[(i4 * 4 + s) * 132 + dk0];
#pragma unroll
                    for (int e = 0; e < 8; ++e) acc[e] += uu[s] * kr[e];
                }
            }
#pragma unroll
            for (int e = 0; e < 8; ++e) St[cL * 132 + dk0 + e] = acc[e];
        }
        __syncthreads();
    }
}

// ---------------------------------------------------------------------------
// D3: o = scale * (o + M U), all fp32 (round-3 verified version)
// ---------------------------------------------------------------------------
__global__ __launch_bounds__(256) void outk_kernel(
    const float* __restrict__ Ug, const float* __restrict__ Mg,
    float* __restrict__ o)
{
    __shared__ float Msh[64 * 68];
    __shared__ float Ush[64 * 68];

    const int c = blockIdx.x, h = blockIdx.y;
    const int dvb = blockIdx.z * 64;
    const int tid = threadIdx.x;
    const size_t hc = (size_t)(h * NC + c);

    for (int e = 0; e < 16; ++e) {
        int idx = e * 256 + tid;
        Msh[(idx >> 6) * 68 + (idx & 63)] = Mg[hc * CH * CH + idx];
    }
    for (int e = 0; e < 16; ++e) {
        int idx = e * 256 + tid;
        int j = idx >> 6, cc = idx & 63;
        Ush[j * 68 + cc] = Ug[hc * CH * 128 + (size_t)j * 128 + dvb + cc];
    }
    __syncthreads();

    const int tx = tid & 15, ty = tid >> 4;
    const int c0 = tx * 4, i0 = ty * 4;
    float acc[4][4] = {{0}};
    for (int j4 = 0; j4 < 16; ++j4) {
        float uv[4][4];
#pragma unroll
        for (int s = 0; s < 4; ++s) {
            float4 u4 = *(const float4*)&Ush[(j4 * 4 + s) * 68 + c0];
            uv[s][0] = u4.x; uv[s][1] = u4.y; uv[s][2] = u4.z; uv[s][3] = u4.w;
        }
#pragma unroll
        for (int r = 0; r < 4; ++r) {
            float4 m4 = *(const float4*)&Msh[(i0 + r) * 68 + j4 * 4];
            const float mv[4] = {m4.x, m4.y, m4.z, m4.w};
#pragma unroll
            for (int s = 0; s < 4; ++s)
#pragma unroll
                for (int e = 0; e < 4; ++e) acc[r][e] += mv[s] * uv[s][e];
        }
    }
    const float scale = 0.08838834764831845f;
#pragma unroll
    for (int r = 0; r < 4; ++r) {
        float* op = &o[(size_t)(c * CH + i0 + r) * HID + h * DV + dvb + c0];
        float4 prev = *(const float4*)op;
        float4 ov = make_float4(scale * (prev.x + acc[r][0]),
                                scale * (prev.y + acc[r][1]),
                                scale * (prev.z + acc[r][2]),
                                scale * (prev.w + acc[r][3]));
        *(float4*)op = ov;
    }
}

// ---------------------------------------------------------------------------
// Gated RMSNorm: gsil bf16 in, onorm (hi,lo) bf16 out
// ---------------------------------------------------------------------------
__global__ __launch_bounds__(256) void normgate_kernel(const float* __restrict__ o,
                                                       const unsigned short* __restrict__ gsil,
                                                       const float* __restrict__ nw,
                                                       unsigned short* __restrict__ out_hi,
                                                       unsigned short* __restrict__ out_lo) {
    const int gw = (blockIdx.x * 256 + threadIdx.x) >> 6;
    const int lane = threadIdx.x & 63;
    if (gw >= T * NH) return;
    const int t = gw / NH, h = gw % NH;
    const size_t base = (size_t)t * HID + h * DV;
    const float a = o[base + lane];
    const float b = o[base + lane + 64];
    float ss = a * a + b * b;
    ss += __shfl_xor(ss, 1);  ss += __shfl_xor(ss, 2);  ss += __shfl_xor(ss, 4);
    ss += __shfl_xor(ss, 8);  ss += __shfl_xor(ss, 16); ss += __shfl_xor(ss, 32);
    const float r = rsqrtf(ss * (1.0f / 128.0f) + 1e-5f);
    float va = a * r * nw[lane]      * bf2f(gsil[base + lane]);
    float vb = b * r * nw[lane + 64] * bf2f(gsil[base + lane + 64]);
    unsigned short ha = f2bf(va), hb = f2bf(vb);
    out_hi[base + lane]      = ha;  out_lo[base + lane]      = f2bf(va - bf2f(ha));
    out_hi[base + lane + 64] = hb;  out_lo[base + lane + 64] = f2bf(vb - bf2f(hb));
}

// ---------------------------------------------------------------------------
extern "C" void kernel_launch(void* const* d_in, const int* in_sizes, int n_in,
                              void* d_out, int out_size, void* d_ws, size_t ws_size,
                              hipStream_t stream) {
    const float* hs      = (const float*)d_in[0];
    const float* Wq      = (const float*)d_in[1];
    const float* Wk      = (const float*)d_in[2];
    const float* Wv      = (const float*)d_in[3];
    const float* Wb      = (const float*)d_in[4];
    const float* Wa      = (const float*)d_in[5];
    const float* A_log   = (const float*)d_in[6];
    const float* dt_bias = (const float*)d_in[7];
    const float* Wg1     = (const float*)d_in[8];
    const float* Wg2     = (const float*)d_in[9];
    const float* Wgate   = (const float*)d_in[10];
    const float* norm_w  = (const float*)d_in[11];
    const float* Wo      = (const float*)d_in[12];

    float* ws = (float*)d_ws;
    // ---- workspace layout (floats), end = 23,740,416 f = 95.0 MB ----
    float* q    = ws;                      // [0, 3145728)   fp32; tail: WoT hi/lo
    float* kbuf = ws + 3145728;            // fp32 k
    float* vpre = ws + 6291456;            // fp32; tail: onorm hi/lo
    float* vbuf = ws + 9437184;            // fp32 v / o; early: hsb hi/lo
    unsigned short* gsil = (unsigned short*)(ws + 12582912);   // bf16 (3.1M shorts)
    // region B [14155776, 22044672): WT hi/lo -> wcv bf16 -> X1/X2/M
    unsigned short* WTh = (unsigned short*)(ws + 14155776);    // 4608x1536 bf16
    unsigned short* WTl = (unsigned short*)(ws + 17694720);
    float* w1f  = ws + 21233664;           // 2048x192 fp32 (gap in region B)
    unsigned short* wcv = (unsigned short*)(ws + 14155776);    // 2048x6144 bf16
    float* X1g  = ws + 14155776;           // 3,145,728 (becomes U in-place)
    float* X2g  = ws + 17301504;           // 3,145,728
    float* Mg   = ws + 20447232;           // 1,572,864
    // region C (persistent smalls)
    unsigned short* WG2Th = (unsigned short*)(ws + 22044672);  // 6144x192 bf16
    unsigned short* WG2Tl = (unsigned short*)(ws + 22634496);
    unsigned short* w1h   = (unsigned short*)(ws + 23224320);  // 2048x192 bf16
    unsigned short* w1l   = (unsigned short*)(ws + 23420928);
    float* bgraw = ws + 23617536;          // 2048x24
    float* beta  = ws + 23666688;
    float* g     = ws + 23691264;
    float* csg   = ws + 23715840;
    // early/tail overlays
    unsigned short* hsbh = (unsigned short*)(ws + 9437184);    // in vbuf region
    unsigned short* hsbl = (unsigned short*)(ws + 11010048);
    unsigned short* WoTh = (unsigned short*)(ws);              // in q region (after state)
    unsigned short* WoTl = (unsigned short*)(ws + 1179648);
    unsigned short* onh  = (unsigned short*)(ws + 6291456);    // in vpre region
    unsigned short* onl  = (unsigned short*)(ws + 7864320);

    const dim3 blk(256);
    const dim3 blkT(32, 8);

    // P0: split hs; transsplit projection batch A = [Wq|Wk|Wv]
    splitcast_kernel<<<3072, blk, 0, stream>>>(hs, hsbh, hsbl, (T * HID) / 4);
    transsplit_kernel<<<dim3(48, 48), blkT, 0, stream>>>(Wq, WTh,               WTl,               1536, 1536);
    transsplit_kernel<<<dim3(48, 48), blkT, 0, stream>>>(Wk, WTh + 1536 * 1536, WTl + 1536 * 1536, 1536, 1536);
    transsplit_kernel<<<dim3(48, 48), blkT, 0, stream>>>(Wv, WTh + 3072 * 1536, WTl + 3072 * 1536, 1536, 1536);

    // P1a: q|k|v projection (N=4608)
    mgemm<1><<<dim3(36, 16), blk, 0, stream>>>(hsbh, hsbl, WTh, WTl, 1536, 4608,
        nullptr, nullptr, q, kbuf, vpre, nullptr, nullptr, nullptr);

    // P1b: gate|w1|bg projection (N=1792), reusing the WT buffer
    transsplit_kernel<<<dim3(48, 48), blkT, 0, stream>>>(Wgate, WTh,               WTl,               1536, 1536);
    transsplit_kernel<<<dim3(6, 48),  blkT, 0, stream>>>(Wg1,   WTh + 1536 * 1536, WTl + 1536 * 1536, 1536, 192);
    transsplit_kernel<<<dim3(1, 48),  blkT, 0, stream>>>(Wb,    WTh + 1728 * 1536, WTl + 1728 * 1536, 1536, 12);
    transsplit_kernel<<<dim3(1, 48),  blkT, 0, stream>>>(Wa,    WTh + 1740 * 1536, WTl + 1740 * 1536, 1536, 12);
    mgemm<2><<<dim3(14, 16), blk, 0, stream>>>(hsbh, hsbl, WTh, WTl, 1536, 1792,
        nullptr, nullptr, nullptr, nullptr, nullptr, gsil, w1f, bgraw);
    bg2_kernel<<<192, blk, 0, stream>>>(bgraw, A_log, dt_bias, beta, g);
    splitcast_kernel<<<384, blk, 0, stream>>>(w1f, w1h, w1l, (2048 * 192) / 4);

    // P2: conv weights GEMM (bf16 out) + conv
    transsplit_kernel<<<dim3(192, 6), blkT, 0, stream>>>(Wg2, WG2Th, WG2Tl, 192, 6144);
    mgemm<3><<<dim3(48, 16), blk, 0, stream>>>(w1h, w1l, WG2Th, WG2Tl, 192, 6144,
        nullptr, wcv, nullptr, nullptr, nullptr, nullptr, nullptr, nullptr);
    conv_kernel<<<(T * HID) / 256, blk, 0, stream>>>(vpre, wcv, vbuf);

    // P3: chunked delta rule (fp32)
    chunkloc_kernel<<<dim3(NC, NH), blk, 0, stream>>>(q, kbuf, vbuf, g, beta,
                                                      X1g, X2g, Mg, csg);
    state_kernel<<<dim3(NH, 8), blk, 0, stream>>>(kbuf, q, X1g, X2g, csg, vbuf);
    transsplit_kernel<<<dim3(48, 48), blkT, 0, stream>>>(Wo, WoTh, WoTl, 1536, 1536);
    outk_kernel<<<dim3(NC, NH, 2), blk, 0, stream>>>(X1g, Mg, vbuf);

    // P4: norm + output GEMM
    normgate_kernel<<<6144, blk, 0, stream>>>(vbuf, gsil, norm_w, onh, onl);
    mgemm<0><<<dim3(12, 16), blk, 0, stream>>>(onh, onl, WoTh, WoTl, 1536, 1536,
        (float*)d_out, nullptr, nullptr, nullptr, nullptr, nullptr, nullptr, nullptr);
}